// Round 1
// baseline (5978.679 us; speedup 1.0000x reference)
//
#include <hip/hip_runtime.h>
#include <math.h>

// ---------------- constants ----------------
// B=32, HID=256, D=64, K=512
// L1: conv 3->256 4x4 s2 p1, 128->64   | BN+ReLU
// L2: conv 256->256 4x4 s2 p1, 64->32  | BN+ReLU
// L3: conv 3x3 s1 p1 + res             | L4: conv 1x1 + res
// L5: conv 1x1 256->64 -> enc
// VQ; L6: conv 1x1 64->256
// L7/L8: conv 3x3 + res
// L9: deconv 4x4 s2 p1 256->256, 32->64 | BN+ReLU
// L10: deconv 256->3, 64->128 | sigmoid -> d_out

#define OUT_CLOSEST 1572864
#define OUT_QLOSS   1605632

// ws offsets (floats)
#define OFF_BIG   0u
#define OFF_BP    0u           // aliases BIG (dead h1 region)
#define OFF_ENC   8388608u     // inside BIG
#define OFF_QO    10485760u    // inside BIG
#define OFF_S     33554432u
#define OFF_W2T   41943040u
#define OFF_RW1T  42991616u
#define OFF_RW2T  43581440u
#define OFF_PWT   43646976u
#define OFF_DPWT  43663360u
#define OFF_DRW1T 43679744u
#define OFF_DRW2T 44269568u
#define OFF_TW1T  44859392u
#define OFF_TW2T  45907968u
#define OFF_STATS 45920256u
#define OFF_NORM  45920768u    // 512 doubles
#define OFF_CIDX  45921792u    // 32768 ints
#define OFF_PART  45954560u    // 8192 floats

// ---------------- weight permutes ----------------
// conv weight (CO,CI,KH,KW) -> (T, CI, CO)
__global__ __launch_bounds__(256) void wperm(const float* __restrict__ w, float* __restrict__ o,
                                             int CO, int CI, int T, int n) {
  int i = blockIdx.x * 256 + threadIdx.x;
  if (i >= n) return;
  int t = i % T; int r = i / T; int ci = r % CI; int co = r / CI;
  o[((size_t)t * CI + ci) * CO + co] = w[i];
}
// deconv weight (CI,CO,KH,KW) -> (T, CI, CO)
__global__ __launch_bounds__(256) void wpermT(const float* __restrict__ w, float* __restrict__ o,
                                              int CI, int CO, int T, int n) {
  int i = blockIdx.x * 256 + threadIdx.x;
  if (i >= n) return;
  int t = i % T; int r = i / T; int co = r % CO; int ci = r / CO;
  o[((size_t)t * CI + ci) * CO + co] = w[i];
}

// ---------------- L1 direct conv ----------------
__global__ __launch_bounds__(256) void conv1_k(const float* __restrict__ x, const float* __restrict__ w,
                                               const float* __restrict__ bias, float* __restrict__ out) {
  int tid = threadIdx.x;
  int ow = tid & 63, ohl = tid >> 6;
  int oh = blockIdx.x * 4 + ohl;
  int co = blockIdx.y, b = blockIdx.z;
  float acc = bias[co];
  for (int ci = 0; ci < 3; ++ci) {
    const float* xb = x + (size_t)(b * 3 + ci) * 16384;
    for (int kh = 0; kh < 4; ++kh) {
      int ih = oh * 2 + kh - 1;
      if ((unsigned)ih >= 128u) continue;
      for (int kw = 0; kw < 4; ++kw) {
        int iw = ow * 2 + kw - 1;
        if ((unsigned)iw >= 128u) continue;
        acc = fmaf(xb[ih * 128 + iw], w[((co * 3 + ci) * 4 + kh) * 4 + kw], acc);
      }
    }
  }
  out[(size_t)(b * 256 + co) * 4096 + oh * 64 + ow] = acc;
}

// ---------------- BN ----------------
__global__ __launch_bounds__(256) void bn_stats(const float* __restrict__ in, float* __restrict__ stats,
                                                int log2HW, int Bn) {
  int c = blockIdx.x;               // 0..255
  int tid = threadIdx.x;
  int HW = 1 << log2HW;
  int cnt = Bn << log2HW;
  double s = 0.0, s2 = 0.0;
  for (int i = tid; i < cnt; i += 256) {
    int b = i >> log2HW, p = i & (HW - 1);
    float v = in[((size_t)(b * 256 + c) << log2HW) + p];
    s += v; s2 += (double)v * v;
  }
  __shared__ double r1[256], r2[256];
  r1[tid] = s; r2[tid] = s2;
  __syncthreads();
  for (int st = 128; st > 0; st >>= 1) {
    if (tid < st) { r1[tid] += r1[tid + st]; r2[tid] += r2[tid + st]; }
    __syncthreads();
  }
  if (tid == 0) {
    double m = r1[0] / cnt;
    double var = r2[0] / cnt - m * m;
    stats[c] = (float)m;
    stats[256 + c] = (float)(1.0 / sqrt(var + 1e-5));
  }
}

// y = [res +] relu((x-m)*istd*g + be), float4-vectorized, in-place safe
__global__ __launch_bounds__(256) void bn_apply(const float4* __restrict__ in, const float4* __restrict__ res,
                                                float4* __restrict__ out, const float* __restrict__ stats,
                                                const float* __restrict__ g, const float* __restrict__ be,
                                                int log2HW, int n4) {
  int i = blockIdx.x * 256 + threadIdx.x;
  if (i >= n4) return;
  int c = (i >> (log2HW - 2)) & 255;
  float sc = stats[256 + c] * g[c];
  float sh = be[c] - stats[c] * sc;
  float4 v = in[i];
  float4 o;
  o.x = fmaxf(fmaf(v.x, sc, sh), 0.f);
  o.y = fmaxf(fmaf(v.y, sc, sh), 0.f);
  o.z = fmaxf(fmaf(v.z, sc, sh), 0.f);
  o.w = fmaxf(fmaf(v.w, sc, sh), 0.f);
  if (res) { float4 r = res[i]; o.x += r.x; o.y += r.y; o.z += r.z; o.w += r.w; }
  out[i] = o;
}

// ---------------- tiled conv (generic) ----------------
__device__ __forceinline__ void tile_fma(const float* Ws_, const float* Xs_, int co4, int sp4,
                                         float acc[4][4]) {
#pragma unroll
  for (int ci = 0; ci < 16; ++ci) {
    float4 wv = *(const float4*)(Ws_ + (ci << 6) + co4);
    float4 xv = *(const float4*)(Xs_ + (ci << 6) + sp4);
    acc[0][0] = fmaf(xv.x, wv.x, acc[0][0]);
    acc[0][1] = fmaf(xv.x, wv.y, acc[0][1]);
    acc[0][2] = fmaf(xv.x, wv.z, acc[0][2]);
    acc[0][3] = fmaf(xv.x, wv.w, acc[0][3]);
    acc[1][0] = fmaf(xv.y, wv.x, acc[1][0]);
    acc[1][1] = fmaf(xv.y, wv.y, acc[1][1]);
    acc[1][2] = fmaf(xv.y, wv.z, acc[1][2]);
    acc[1][3] = fmaf(xv.y, wv.w, acc[1][3]);
    acc[2][0] = fmaf(xv.z, wv.x, acc[2][0]);
    acc[2][1] = fmaf(xv.z, wv.y, acc[2][1]);
    acc[2][2] = fmaf(xv.z, wv.z, acc[2][2]);
    acc[2][3] = fmaf(xv.z, wv.w, acc[2][3]);
    acc[3][0] = fmaf(xv.w, wv.x, acc[3][0]);
    acc[3][1] = fmaf(xv.w, wv.y, acc[3][1]);
    acc[3][2] = fmaf(xv.w, wv.z, acc[3][2]);
    acc[3][3] = fmaf(xv.w, wv.w, acc[3][3]);
  }
}

__global__ __launch_bounds__(256) void conv_tiled(
    const float* __restrict__ in, const float* __restrict__ wt,
    const float* __restrict__ bias, float* __restrict__ out,
    int CI, int CO, int Hin, int Win, int Hout, int Wout,
    int KH, int KW, int stride, int pad) {
  __shared__ float Xs[16 * 64];
  __shared__ float Ws[16 * 64];
  const int tid = threadIdx.x;
  const int b = blockIdx.z;
  const int co_base = blockIdx.y << 6;
  const int sp_base = blockIdx.x << 6;
  const int lo = tid & 15, hi = tid >> 4;
  const int co4 = lo << 2, sp4 = hi << 2;
  const int HWin = Hin * Win, HWout = Hout * Wout;

  int oh0[4], ow0[4];
#pragma unroll
  for (int j = 0; j < 4; ++j) {
    int s = sp_base + (lo << 2) + j;
    oh0[j] = s / Wout; ow0[j] = s - oh0[j] * Wout;
  }
  float acc[4][4] = {{0.f, 0.f, 0.f, 0.f}, {0.f, 0.f, 0.f, 0.f},
                     {0.f, 0.f, 0.f, 0.f}, {0.f, 0.f, 0.f, 0.f}};

  for (int kh = 0; kh < KH; ++kh)
    for (int kw = 0; kw < KW; ++kw) {
      const int t = kh * KW + kw;
      for (int ci0 = 0; ci0 < CI; ci0 += 16) {
        const float* ib = in + (size_t)(b * CI + ci0 + hi) * HWin;
        float v[4];
#pragma unroll
        for (int j = 0; j < 4; ++j) {
          int ih = oh0[j] * stride + kh - pad;
          int iw = ow0[j] * stride + kw - pad;
          v[j] = 0.f;
          if ((unsigned)ih < (unsigned)Hin && (unsigned)iw < (unsigned)Win)
            v[j] = ib[ih * Win + iw];
        }
        *(float4*)&Xs[(hi << 6) + (lo << 2)] = make_float4(v[0], v[1], v[2], v[3]);
        *(float4*)&Ws[(hi << 6) + (lo << 2)] =
            *(const float4*)&wt[((size_t)t * CI + ci0 + hi) * CO + co_base + (lo << 2)];
        __syncthreads();
        tile_fma(Ws, Xs, co4, sp4, acc);
        __syncthreads();
      }
    }
#pragma unroll
  for (int i = 0; i < 4; ++i) {
    int co = co_base + co4 + i;
    float bv = bias[co];
    float4 r = make_float4(acc[0][i] + bv, acc[1][i] + bv, acc[2][i] + bv, acc[3][i] + bv);
    *(float4*)&out[(size_t)(b * CO + co) * HWout + sp_base + sp4] = r;
  }
}

// ---------------- tiled deconv (L9): in 32x32 -> out 64x64, k4 s2 p1 ----------------
__global__ __launch_bounds__(256) void deconv_tiled(
    const float* __restrict__ in, const float* __restrict__ wt,
    const float* __restrict__ bias, float* __restrict__ out, int CI, int CO) {
  __shared__ float Xs[16 * 64];
  __shared__ float Ws[16 * 64];
  const int tid = threadIdx.x;
  const int bz = blockIdx.z;
  const int b = bz >> 2, ph = (bz >> 1) & 1, pw = bz & 1;
  const int co_base = blockIdx.y << 6;
  const int sp_base = blockIdx.x << 6;
  const int lo = tid & 15, hi = tid >> 4;
  const int co4 = lo << 2, sp4 = hi << 2;
  int khs[2], dhs[2], kws[2], dws[2];
  if (ph == 0) { khs[0] = 1; dhs[0] = 0; khs[1] = 3; dhs[1] = -1; }
  else         { khs[0] = 0; dhs[0] = 1; khs[1] = 2; dhs[1] = 0; }
  if (pw == 0) { kws[0] = 1; dws[0] = 0; kws[1] = 3; dws[1] = -1; }
  else         { kws[0] = 0; dws[0] = 1; kws[1] = 2; dws[1] = 0; }
  int av[4], cv[4];
#pragma unroll
  for (int j = 0; j < 4; ++j) { int s = sp_base + (lo << 2) + j; av[j] = s >> 5; cv[j] = s & 31; }
  float acc[4][4] = {{0.f, 0.f, 0.f, 0.f}, {0.f, 0.f, 0.f, 0.f},
                     {0.f, 0.f, 0.f, 0.f}, {0.f, 0.f, 0.f, 0.f}};
  for (int ti = 0; ti < 2; ++ti)
    for (int tj = 0; tj < 2; ++tj) {
      const int kh = khs[ti], dh = dhs[ti], kw = kws[tj], dw = dws[tj];
      const int t = (kh << 2) + kw;
      for (int ci0 = 0; ci0 < CI; ci0 += 16) {
        const float* ib = in + (size_t)(b * CI + ci0 + hi) * 1024;
        float v[4];
#pragma unroll
        for (int j = 0; j < 4; ++j) {
          int ih = av[j] + dh, iw = cv[j] + dw;
          v[j] = ((unsigned)ih < 32u && (unsigned)iw < 32u) ? ib[(ih << 5) + iw] : 0.f;
        }
        *(float4*)&Xs[(hi << 6) + (lo << 2)] = make_float4(v[0], v[1], v[2], v[3]);
        *(float4*)&Ws[(hi << 6) + (lo << 2)] =
            *(const float4*)&wt[((size_t)t * CI + ci0 + hi) * CO + co_base + (lo << 2)];
        __syncthreads();
        tile_fma(Ws, Xs, co4, sp4, acc);
        __syncthreads();
      }
    }
#pragma unroll
  for (int i = 0; i < 4; ++i) {
    int co = co_base + co4 + i;
    float bv = bias[co];
#pragma unroll
    for (int j = 0; j < 4; ++j) {
      int s = sp_base + sp4 + j;
      int a = s >> 5, c = s & 31;
      out[((size_t)(b * CO + co) << 12) + ((2 * a + ph) << 6) + 2 * c + pw] = acc[j][i] + bv;
    }
  }
}

// ---------------- L10: deconv 256->3 + sigmoid -> d_out ----------------
__global__ __launch_bounds__(256) void deconv_final(const float* __restrict__ in, const float* __restrict__ wt,
                                                    const float* __restrict__ bias, float* __restrict__ out) {
  int phase = blockIdx.y, ph = phase >> 1, pw = phase & 1;
  int i = blockIdx.x * 256 + threadIdx.x;  // over B*64*64
  int b = i >> 12, p = i & 4095, a = p >> 6, c = p & 63;
  int khs[2], dhs[2], kws[2], dws[2];
  if (ph == 0) { khs[0] = 1; dhs[0] = 0; khs[1] = 3; dhs[1] = -1; }
  else         { khs[0] = 0; dhs[0] = 1; khs[1] = 2; dhs[1] = 0; }
  if (pw == 0) { kws[0] = 1; dws[0] = 0; kws[1] = 3; dws[1] = -1; }
  else         { kws[0] = 0; dws[0] = 1; kws[1] = 2; dws[1] = 0; }
  float a0 = bias[0], a1 = bias[1], a2 = bias[2];
  for (int ci = 0; ci < 256; ++ci) {
    const float* xb = in + ((size_t)(b * 256 + ci) << 12);
    for (int t = 0; t < 4; ++t) {
      int kh = khs[t >> 1], dh = dhs[t >> 1], kw = kws[t & 1], dw = dws[t & 1];
      int ih = a + dh, iw = c + dw;
      if ((unsigned)ih < 64u && (unsigned)iw < 64u) {
        float v = xb[(ih << 6) + iw];
        const float* wp = &wt[(((kh << 2) + kw) * 256 + ci) * 3];
        a0 = fmaf(v, wp[0], a0);
        a1 = fmaf(v, wp[1], a1);
        a2 = fmaf(v, wp[2], a2);
      }
    }
  }
  int oh = 2 * a + ph, ow = 2 * c + pw;
  size_t o = ((size_t)b * 3) * 16384 + (oh << 7) + ow;
  out[o] = 1.f / (1.f + __expf(-a0));
  out[o + 16384] = 1.f / (1.f + __expf(-a1));
  out[o + 32768] = 1.f / (1.f + __expf(-a2));
}

// ---------------- VQ ----------------
__global__ __launch_bounds__(256) void cb_norms(const float* __restrict__ emb, double* __restrict__ norms) {
  int k = blockIdx.x * 256 + threadIdx.x;
  if (k >= 512) return;
  double s = 0.0;
  for (int d = 0; d < 64; ++d) { double e = emb[(k << 6) + d]; s += e * e; }
  norms[k] = s;
}

__global__ __launch_bounds__(256) void vq_argmin(const float* __restrict__ enc, const float* __restrict__ emb,
                                                 const double* __restrict__ norms, int* __restrict__ cidx,
                                                 float* __restrict__ closest_out) {
  __shared__ float se[128 * 64];  // 32KB: quarter of the codebook
  int tid = threadIdx.x;
  int r = blockIdx.x * 256 + tid;
  double ef[64];
  const float4* ep = (const float4*)(enc + ((size_t)r << 6));
#pragma unroll
  for (int q = 0; q < 16; ++q) {
    float4 v = ep[q];
    ef[4 * q] = v.x; ef[4 * q + 1] = v.y; ef[4 * q + 2] = v.z; ef[4 * q + 3] = v.w;
  }
  double best = 1e300; int bi = 0;
  for (int q = 0; q < 4; ++q) {
    __syncthreads();
    for (int i = tid; i < 8192; i += 256) se[i] = emb[q * 8192 + i];
    __syncthreads();
    for (int k = 0; k < 128; ++k) {
      const float* cp = &se[k << 6];
      double dot = 0.0;
#pragma unroll
      for (int d = 0; d < 64; ++d) dot = fma(ef[d], (double)cp[d], dot);
      // |ef|^2 is common across k -> omit (argmin-invariant, kills common-mode rounding)
      double d2 = norms[q * 128 + k] - 2.0 * dot;
      if (d2 < best) { best = d2; bi = q * 128 + k; }
    }
  }
  cidx[r] = bi;
  closest_out[r] = (float)bi;
}

__global__ __launch_bounds__(256) void vq_gather(const float* __restrict__ enc, const float* __restrict__ emb,
                                                 const int* __restrict__ cidx, float* __restrict__ qo,
                                                 float* __restrict__ part) {
  int tid = threadIdx.x;
  int i = blockIdx.x * 256 + tid;
  int r = i >> 6, d = i & 63;
  int k = cidx[r];
  float q = emb[(k << 6) + d];
  float e = enc[i];
  qo[i] = q;
  float df = q - e;
  __shared__ float red[256];
  red[tid] = df * df;
  __syncthreads();
  for (int st = 128; st > 0; st >>= 1) {
    if (tid < st) red[tid] += red[tid + st];
    __syncthreads();
  }
  if (tid == 0) part[blockIdx.x] = red[0];
}

__global__ __launch_bounds__(256) void qloss_final(const float* __restrict__ part, float* __restrict__ out) {
  int tid = threadIdx.x;
  double s = 0.0;
  for (int i = tid; i < 8192; i += 256) s += part[i];
  __shared__ double red[256];
  red[tid] = s;
  __syncthreads();
  for (int st = 128; st > 0; st >>= 1) {
    if (tid < st) red[tid] += red[tid + st];
    __syncthreads();
  }
  if (tid == 0) {
    double mean = red[0] / 2097152.0;
    out[0] = (float)(1.25 * mean);  // codebook + 0.25*commit, equal in fwd value
  }
}

// ---------------- host ----------------
extern "C" void kernel_launch(void* const* d_in, const int* in_sizes, int n_in,
                              void* d_out, int out_size, void* d_ws, size_t ws_size,
                              hipStream_t stream) {
  const float* x     = (const float*)d_in[0];
  const float* emb   = (const float*)d_in[1];
  const float* e_w1  = (const float*)d_in[2];
  const float* e_b1  = (const float*)d_in[3];
  const float* e_g1  = (const float*)d_in[4];
  const float* e_be1 = (const float*)d_in[5];
  const float* e_w2  = (const float*)d_in[6];
  const float* e_b2  = (const float*)d_in[7];
  const float* e_g2  = (const float*)d_in[8];
  const float* e_be2 = (const float*)d_in[9];
  const float* e_rw1 = (const float*)d_in[10];
  const float* e_rb1 = (const float*)d_in[11];
  const float* e_rg1 = (const float*)d_in[12];
  const float* e_rbe1= (const float*)d_in[13];
  const float* e_rw2 = (const float*)d_in[14];
  const float* e_rb2 = (const float*)d_in[15];
  const float* e_rg2 = (const float*)d_in[16];
  const float* e_rbe2= (const float*)d_in[17];
  const float* e_pw  = (const float*)d_in[18];
  const float* e_pb  = (const float*)d_in[19];
  const float* d_pw  = (const float*)d_in[20];
  const float* d_pb  = (const float*)d_in[21];
  const float* d_rw1 = (const float*)d_in[22];
  const float* d_rb1 = (const float*)d_in[23];
  const float* d_rg1 = (const float*)d_in[24];
  const float* d_rbe1= (const float*)d_in[25];
  const float* d_rw2 = (const float*)d_in[26];
  const float* d_rb2 = (const float*)d_in[27];
  const float* d_rg2 = (const float*)d_in[28];
  const float* d_rbe2= (const float*)d_in[29];
  const float* d_tw1 = (const float*)d_in[30];
  const float* d_tb1 = (const float*)d_in[31];
  const float* d_tg1 = (const float*)d_in[32];
  const float* d_tbe1= (const float*)d_in[33];
  const float* d_tw2 = (const float*)d_in[34];
  const float* d_tb2 = (const float*)d_in[35];

  float* ws   = (float*)d_ws;
  float* BIG  = ws + OFF_BIG;
  float* BP   = ws + OFF_BP;
  float* ENC  = ws + OFF_ENC;
  float* QO   = ws + OFF_QO;
  float* S    = ws + OFF_S;
  float* W2T  = ws + OFF_W2T;
  float* RW1T = ws + OFF_RW1T;
  float* RW2T = ws + OFF_RW2T;
  float* PWT  = ws + OFF_PWT;
  float* DPWT = ws + OFF_DPWT;
  float* DRW1T= ws + OFF_DRW1T;
  float* DRW2T= ws + OFF_DRW2T;
  float* TW1T = ws + OFF_TW1T;
  float* TW2T = ws + OFF_TW2T;
  float* STATS= ws + OFF_STATS;
  double* NORM= (double*)(ws + OFF_NORM);
  int*   CIDX = (int*)(ws + OFF_CIDX);
  float* PART = ws + OFF_PART;
  float* outp = (float*)d_out;

  dim3 blk(256);

  // weight permutes + codebook norms
  wperm <<<4096, blk, 0, stream>>>(e_w2,  W2T,  256, 256, 16, 1048576);
  wperm <<<2304, blk, 0, stream>>>(e_rw1, RW1T, 256, 256, 9,  589824);
  wperm <<<256,  blk, 0, stream>>>(e_rw2, RW2T, 256, 256, 1,  65536);
  wperm <<<64,   blk, 0, stream>>>(e_pw,  PWT,  64,  256, 1,  16384);
  wperm <<<64,   blk, 0, stream>>>(d_pw,  DPWT, 256, 64,  1,  16384);
  wperm <<<2304, blk, 0, stream>>>(d_rw1, DRW1T,256, 256, 9,  589824);
  wperm <<<2304, blk, 0, stream>>>(d_rw2, DRW2T,256, 256, 9,  589824);
  wpermT<<<4096, blk, 0, stream>>>(d_tw1, TW1T, 256, 256, 16, 1048576);
  wpermT<<<48,   blk, 0, stream>>>(d_tw2, TW2T, 256, 3,   16, 12288);
  cb_norms<<<2, blk, 0, stream>>>(emb, NORM);

  // ---- encoder ----
  // L1
  conv1_k<<<dim3(16, 256, 32), blk, 0, stream>>>(x, e_w1, e_b1, BIG);
  bn_stats<<<256, blk, 0, stream>>>(BIG, STATS, 12, 32);
  bn_apply<<<32768, blk, 0, stream>>>((float4*)BIG, nullptr, (float4*)BIG, STATS, e_g1, e_be1, 12, 8388608);
  // L2
  conv_tiled<<<dim3(16, 4, 32), blk, 0, stream>>>(BIG, W2T, e_b2, S, 256, 256, 64, 64, 32, 32, 4, 4, 2, 1);
  bn_stats<<<256, blk, 0, stream>>>(S, STATS, 10, 32);
  bn_apply<<<8192, blk, 0, stream>>>((float4*)S, nullptr, (float4*)S, STATS, e_g2, e_be2, 10, 2097152);
  // L3 (res 3x3)
  conv_tiled<<<dim3(16, 4, 32), blk, 0, stream>>>(S, RW1T, e_rb1, BP, 256, 256, 32, 32, 32, 32, 3, 3, 1, 1);
  bn_stats<<<256, blk, 0, stream>>>(BP, STATS, 10, 32);
  bn_apply<<<8192, blk, 0, stream>>>((float4*)BP, (float4*)S, (float4*)BP, STATS, e_rg1, e_rbe1, 10, 2097152);
  // L4 (res 1x1)
  conv_tiled<<<dim3(16, 4, 32), blk, 0, stream>>>(BP, RW2T, e_rb2, S, 256, 256, 32, 32, 32, 32, 1, 1, 1, 0);
  bn_stats<<<256, blk, 0, stream>>>(S, STATS, 10, 32);
  bn_apply<<<8192, blk, 0, stream>>>((float4*)S, (float4*)BP, (float4*)S, STATS, e_rg2, e_rbe2, 10, 2097152);
  // L5 -> enc
  conv_tiled<<<dim3(16, 1, 32), blk, 0, stream>>>(S, PWT, e_pb, ENC, 256, 64, 32, 32, 32, 32, 1, 1, 1, 0);

  // ---- VQ ----
  vq_argmin<<<128, blk, 0, stream>>>(ENC, emb, NORM, CIDX, outp + OUT_CLOSEST);
  vq_gather<<<8192, blk, 0, stream>>>(ENC, emb, CIDX, QO, PART);
  qloss_final<<<1, blk, 0, stream>>>(PART, outp + OUT_QLOSS);

  // ---- decoder ----
  // L6 (1x1 64->256, bias only)
  conv_tiled<<<dim3(16, 4, 32), blk, 0, stream>>>(QO, DPWT, d_pb, S, 64, 256, 32, 32, 32, 32, 1, 1, 1, 0);
  // L7 (res 3x3)
  conv_tiled<<<dim3(16, 4, 32), blk, 0, stream>>>(S, DRW1T, d_rb1, BP, 256, 256, 32, 32, 32, 32, 3, 3, 1, 1);
  bn_stats<<<256, blk, 0, stream>>>(BP, STATS, 10, 32);
  bn_apply<<<8192, blk, 0, stream>>>((float4*)BP, (float4*)S, (float4*)BP, STATS, d_rg1, d_rbe1, 10, 2097152);
  // L8 (res 3x3)
  conv_tiled<<<dim3(16, 4, 32), blk, 0, stream>>>(BP, DRW2T, d_rb2, S, 256, 256, 32, 32, 32, 32, 3, 3, 1, 1);
  bn_stats<<<256, blk, 0, stream>>>(S, STATS, 10, 32);
  bn_apply<<<8192, blk, 0, stream>>>((float4*)S, (float4*)BP, (float4*)S, STATS, d_rg2, d_rbe2, 10, 2097152);
  // L9 (deconv 256->256)
  deconv_tiled<<<dim3(16, 4, 128), blk, 0, stream>>>(S, TW1T, d_tb1, BIG, 256, 256);
  bn_stats<<<256, blk, 0, stream>>>(BIG, STATS, 12, 32);
  bn_apply<<<32768, blk, 0, stream>>>((float4*)BIG, nullptr, (float4*)BIG, STATS, d_tg1, d_tbe1, 12, 8388608);
  // L10 (deconv 256->3 + sigmoid)
  deconv_final<<<dim3(512, 4), blk, 0, stream>>>(BIG, TW2T, d_tb2, outp);
}

// Round 2
// 4932.652 us; speedup vs baseline: 1.2121x; 1.2121x over previous
//
#include <hip/hip_runtime.h>
#include <hip/hip_bf16.h>
#include <math.h>

// B=32, HID=256, D=64, K=512
// Encoder fp32 (argmin exactness); decoder bf16 MFMA (post-VQ, lenient threshold).

#define OUT_CLOSEST 1572864
#define OUT_QLOSS   1605632

// ---- ws offsets (in floats) ----
#define OFF_BIG   0u
#define OFF_BP    0u          // encoder conv temp / decoder t7,t8 (8.39M fl)
#define OFF_ENC   8388608u    // 2M fl (alias: HT1 after VQ done)
#define OFF_HT1   8388608u    // bf16 8.39M elems (4.19M fl)
#define OFF_HT2   12582912u
#define OFF_HT3   16777216u
#define OFF_QOT   20971520u   // bf16 2M elems (1M fl)
// T9BT = BIG[0 .. 16.78M fl) as bf16 (33.55M elems)
#define OFF_S     33554432u
#define OFF_W2T   41943040u
#define OFF_RW1T  42991616u
#define OFF_RW2T  43581440u
#define OFF_PWT   43646976u
#define OFF_TW2T  43663360u
#define OFF_DPWB  43675648u
#define OFF_DRW1B 43683840u
#define OFF_DRW2B 43978752u
#define OFF_TW1B  44273664u
#define OFF_STATS 44797952u
#define OFF_NORM  44798464u   // 512 doubles
#define OFF_CIDX  44799488u
#define OFF_PART  44832256u
#define OFF_STAT2 44840448u   // 32768 fl

typedef __bf16 bf16x8 __attribute__((ext_vector_type(8)));
typedef float f32x4 __attribute__((ext_vector_type(4)));

__device__ __forceinline__ unsigned short f2bf(float f) {
  __hip_bfloat16 h = __float2bfloat16(f);
  return *reinterpret_cast<unsigned short*>(&h);
}
__device__ __forceinline__ float bf2f(unsigned short u) {
  return __uint_as_float((unsigned)u << 16);
}

// ---------------- weight permutes ----------------
// conv weight (CO,CI,T) flat -> fp32 (T, CI, CO)
__global__ __launch_bounds__(256) void wperm(const float* __restrict__ w, float* __restrict__ o,
                                             int CO, int CI, int T, int n) {
  int i = blockIdx.x * 256 + threadIdx.x;
  if (i >= n) return;
  int t = i % T; int r = i / T; int ci = r % CI; int co = r / CI;
  o[((size_t)t * CI + ci) * CO + co] = w[i];
}
// deconv weight (CI,CO,T) -> fp32 (T, CI, CO)
__global__ __launch_bounds__(256) void wpermT(const float* __restrict__ w, float* __restrict__ o,
                                              int CI, int CO, int T, int n) {
  int i = blockIdx.x * 256 + threadIdx.x;
  if (i >= n) return;
  int t = i % T; int r = i / T; int co = r % CO; int ci = r / CO;
  o[((size_t)t * CI + ci) * CO + co] = w[i];
}
// conv weight (CO,CI,T) -> bf16 (T, CO, CI)
__global__ __launch_bounds__(256) void wpermb(const float* __restrict__ w, __hip_bfloat16* __restrict__ o,
                                              int CO, int CI, int T, int n) {
  int i = blockIdx.x * 256 + threadIdx.x;
  if (i >= n) return;
  int t = i % T; int r = i / T; int ci = r % CI; int co = r / CI;
  o[((size_t)t * CO + co) * CI + ci] = __float2bfloat16(w[i]);
}
// deconv weight (CI,CO,T) -> bf16 (T, CO, CI)
__global__ __launch_bounds__(256) void wpermbT(const float* __restrict__ w, __hip_bfloat16* __restrict__ o,
                                               int CI, int CO, int T, int n) {
  int i = blockIdx.x * 256 + threadIdx.x;
  if (i >= n) return;
  int t = i % T; int r = i / T; int co = r % CO; int ci = r / CO;
  o[((size_t)t * CO + co) * CI + ci] = __float2bfloat16(w[i]);
}

// ---------------- L1 direct conv ----------------
__global__ __launch_bounds__(256) void conv1_k(const float* __restrict__ x, const float* __restrict__ w,
                                               const float* __restrict__ bias, float* __restrict__ out) {
  int tid = threadIdx.x;
  int ow = tid & 63, ohl = tid >> 6;
  int oh = blockIdx.x * 4 + ohl;
  int co = blockIdx.y, b = blockIdx.z;
  float acc = bias[co];
  for (int ci = 0; ci < 3; ++ci) {
    const float* xb = x + (size_t)(b * 3 + ci) * 16384;
    for (int kh = 0; kh < 4; ++kh) {
      int ih = oh * 2 + kh - 1;
      if ((unsigned)ih >= 128u) continue;
      for (int kw = 0; kw < 4; ++kw) {
        int iw = ow * 2 + kw - 1;
        if ((unsigned)iw >= 128u) continue;
        acc = fmaf(xb[ih * 128 + iw], w[((co * 3 + ci) * 4 + kh) * 4 + kw], acc);
      }
    }
  }
  out[(size_t)(b * 256 + co) * 4096 + oh * 64 + ow] = acc;
}

// ---------------- BN (fp32 NCHW) ----------------
__global__ __launch_bounds__(256) void bn_stats(const float* __restrict__ in, float* __restrict__ stats,
                                                int log2HW, int Bn) {
  int c = blockIdx.x;
  int tid = threadIdx.x;
  int HW = 1 << log2HW;
  int cnt = Bn << log2HW;
  double s = 0.0, s2 = 0.0;
  for (int i = tid; i < cnt; i += 256) {
    int b = i >> log2HW, p = i & (HW - 1);
    float v = in[((size_t)(b * 256 + c) << log2HW) + p];
    s += v; s2 += (double)v * v;
  }
  __shared__ double r1[256], r2[256];
  r1[tid] = s; r2[tid] = s2;
  __syncthreads();
  for (int st = 128; st > 0; st >>= 1) {
    if (tid < st) { r1[tid] += r1[tid + st]; r2[tid] += r2[tid + st]; }
    __syncthreads();
  }
  if (tid == 0) {
    double m = r1[0] / cnt;
    double var = r2[0] / cnt - m * m;
    stats[c] = (float)m;
    stats[256 + c] = (float)(1.0 / sqrt(var + 1e-5));
  }
}

__global__ __launch_bounds__(256) void bn_apply(const float4* __restrict__ in, const float4* __restrict__ res,
                                                float4* __restrict__ out, const float* __restrict__ stats,
                                                const float* __restrict__ g, const float* __restrict__ be,
                                                int log2HW, int n4) {
  int i = blockIdx.x * 256 + threadIdx.x;
  if (i >= n4) return;
  int c = (i >> (log2HW - 2)) & 255;
  float sc = stats[256 + c] * g[c];
  float sh = be[c] - stats[c] * sc;
  float4 v = in[i];
  float4 o;
  o.x = fmaxf(fmaf(v.x, sc, sh), 0.f);
  o.y = fmaxf(fmaf(v.y, sc, sh), 0.f);
  o.z = fmaxf(fmaf(v.z, sc, sh), 0.f);
  o.w = fmaxf(fmaf(v.w, sc, sh), 0.f);
  if (res) { float4 r = res[i]; o.x += r.x; o.y += r.y; o.z += r.z; o.w += r.w; }
  out[i] = o;
}

// BN+ReLU+res for decoder 32x32 layers: fp32 NCHW in/res, optional fp32 out,
// bf16 transposed (b, sp, c) out. Thread j over (b, cg=32, sp=1024).
__global__ __launch_bounds__(256) void bn_apply_td(const float* __restrict__ in, const float* __restrict__ res,
                                                   float* __restrict__ out_f, __hip_bfloat16* __restrict__ out_bt,
                                                   const float* __restrict__ stats, const float* __restrict__ g,
                                                   const float* __restrict__ be) {
  int j = blockIdx.x * 256 + threadIdx.x;  // 32*32*1024 = 1,048,576
  int sp = j & 1023, cg = (j >> 10) & 31, b = j >> 15;
  unsigned short us[8];
#pragma unroll
  for (int q = 0; q < 8; ++q) {
    int c = cg * 8 + q;
    float sc = stats[256 + c] * g[c];
    float sh = be[c] - stats[c] * sc;
    size_t idx = ((size_t)(b * 256 + c) << 10) + sp;
    float y = fmaxf(fmaf(in[idx], sc, sh), 0.f) + res[idx];
    if (out_f) out_f[idx] = y;
    us[q] = f2bf(y);
  }
  ushort4* op = (ushort4*)(out_bt + (((size_t)(b << 10) + sp) << 8) + cg * 8);
  op[0] = make_ushort4(us[0], us[1], us[2], us[3]);
  op[1] = make_ushort4(us[4], us[5], us[6], us[7]);
}

// fp32 NCHW (32,256,1024) -> bf16 (b, sp, c)  [for h6]
__global__ __launch_bounds__(256) void fp32_to_bt(const float* __restrict__ in, __hip_bfloat16* __restrict__ out) {
  int j = blockIdx.x * 256 + threadIdx.x;  // 1,048,576
  int sp = j & 1023, cg = (j >> 10) & 31, b = j >> 15;
  unsigned short us[8];
#pragma unroll
  for (int q = 0; q < 8; ++q) {
    int c = cg * 8 + q;
    us[q] = f2bf(in[((size_t)(b * 256 + c) << 10) + sp]);
  }
  ushort4* op = (ushort4*)(out + (((size_t)(b << 10) + sp) << 8) + cg * 8);
  op[0] = make_ushort4(us[0], us[1], us[2], us[3]);
  op[1] = make_ushort4(us[4], us[5], us[6], us[7]);
}

// ---------------- MFMA conv (decoder, 32x32 s1) ----------------
// act: bf16 (b, 1024, CI); wt: bf16 (T, CO, CI); out: fp32 NCHW (b, CO, 1024)
template<int CI, int KH, int KW, int PAD>
__global__ __launch_bounds__(256) void mconv(const __hip_bfloat16* __restrict__ act,
                                             const __hip_bfloat16* __restrict__ wt,
                                             const float* __restrict__ bias,
                                             float* __restrict__ out, int CO) {
  const int tid = threadIdx.x;
  const int lane = tid & 63, wv = tid >> 6;
  const int ln = lane & 15, kg = lane >> 4;
  const int b = blockIdx.z;
  const int co_base = blockIdx.y << 6;
  const int sp_base = blockIdx.x << 6;
  const int co_n = co_base + wv * 16 + ln;
  int oh[4], ow[4];
#pragma unroll
  for (int mf = 0; mf < 4; ++mf) {
    int s = sp_base + mf * 16 + ln;
    oh[mf] = s >> 5; ow[mf] = s & 31;
  }
  f32x4 acc[4] = {{0,0,0,0},{0,0,0,0},{0,0,0,0},{0,0,0,0}};
  const size_t actb = (size_t)b * 1024 * CI;
  const int kg8 = kg * 8;
  for (int kh = 0; kh < KH; ++kh)
    for (int kw = 0; kw < KW; ++kw) {
      const int t = kh * KW + kw;
      const __hip_bfloat16* bp = wt + ((size_t)t * CO + co_n) * CI + kg8;
      const __hip_bfloat16* ap[4]; bool val[4];
#pragma unroll
      for (int mf = 0; mf < 4; ++mf) {
        int ih = oh[mf] + kh - PAD, iw = ow[mf] + kw - PAD;
        val[mf] = ((unsigned)ih < 32u) && ((unsigned)iw < 32u);
        ap[mf] = val[mf] ? (act + actb + (size_t)((ih << 5) + iw) * CI + kg8) : (act + actb + kg8);
      }
#pragma unroll
      for (int ci0 = 0; ci0 < CI; ci0 += 32) {
        bf16x8 bf = *(const bf16x8*)(bp + ci0);
        bf16x8 af[4];
#pragma unroll
        for (int mf = 0; mf < 4; ++mf) {
          bf16x8 z = {};
          bf16x8 tv = *(const bf16x8*)(ap[mf] + ci0);
          af[mf] = val[mf] ? tv : z;
        }
#pragma unroll
        for (int mf = 0; mf < 4; ++mf)
          acc[mf] = __builtin_amdgcn_mfma_f32_16x16x32_bf16(af[mf], bf, acc[mf], 0, 0, 0);
      }
    }
  float bv = bias[co_n];
#pragma unroll
  for (int mf = 0; mf < 4; ++mf) {
    int sp_r = sp_base + mf * 16 + kg * 4;
    float4 r = make_float4(acc[mf][0] + bv, acc[mf][1] + bv, acc[mf][2] + bv, acc[mf][3] + bv);
    *(float4*)&out[((size_t)(b * CO + co_n) << 10) + sp_r] = r;
  }
}

// ---------------- MFMA deconv L9 (swapped operands: A=W, B=act) ----------------
// act: bf16 (b, 1024, 256) h8_t; wt: bf16 (16, 256co, 256ci); out: bf16 (b, 4096, 256)
__global__ __launch_bounds__(256) void mdeconv(const __hip_bfloat16* __restrict__ act,
                                               const __hip_bfloat16* __restrict__ wt,
                                               const float* __restrict__ bias,
                                               __hip_bfloat16* __restrict__ out) {
  const int tid = threadIdx.x;
  const int lane = tid & 63, wv = tid >> 6;
  const int ln = lane & 15, kg = lane >> 4;
  const int bz = blockIdx.z;
  const int b = bz >> 2, ph = (bz >> 1) & 1, pw = bz & 1;
  const int co_base = blockIdx.y << 6;
  const int sp_base = blockIdx.x << 6;
  const int co_a = co_base + wv * 16 + ln;
  int khs[2], dhs[2], kws[2], dws[2];
  if (ph == 0) { khs[0]=1; dhs[0]=0; khs[1]=3; dhs[1]=-1; }
  else         { khs[0]=0; dhs[0]=1; khs[1]=2; dhs[1]=0; }
  if (pw == 0) { kws[0]=1; dws[0]=0; kws[1]=3; dws[1]=-1; }
  else         { kws[0]=0; dws[0]=1; kws[1]=2; dws[1]=0; }
  int a0[4], c0[4];
#pragma unroll
  for (int mf = 0; mf < 4; ++mf) {
    int s = sp_base + mf * 16 + ln;
    a0[mf] = s >> 5; c0[mf] = s & 31;
  }
  f32x4 acc[4] = {{0,0,0,0},{0,0,0,0},{0,0,0,0},{0,0,0,0}};
  const size_t actb = (size_t)b << 18;
  const int kg8 = kg * 8;
  for (int ti = 0; ti < 2; ++ti)
    for (int tj = 0; tj < 2; ++tj) {
      const int t = khs[ti] * 4 + kws[tj];
      const int dh = dhs[ti], dw = dws[tj];
      const __hip_bfloat16* apw = wt + ((size_t)t * 256 + co_a) * 256 + kg8;
      const __hip_bfloat16* bp[4]; bool val[4];
#pragma unroll
      for (int mf = 0; mf < 4; ++mf) {
        int ih = a0[mf] + dh, iw = c0[mf] + dw;
        val[mf] = ((unsigned)ih < 32u) && ((unsigned)iw < 32u);
        bp[mf] = val[mf] ? (act + actb + (size_t)((ih << 5) + iw) * 256 + kg8) : (act + actb + kg8);
      }
#pragma unroll
      for (int ci0 = 0; ci0 < 256; ci0 += 32) {
        bf16x8 af = *(const bf16x8*)(apw + ci0);
        bf16x8 bfr[4];
#pragma unroll
        for (int mf = 0; mf < 4; ++mf) {
          bf16x8 z = {};
          bf16x8 tv = *(const bf16x8*)(bp[mf] + ci0);
          bfr[mf] = val[mf] ? tv : z;
        }
#pragma unroll
        for (int mf = 0; mf < 4; ++mf)
          acc[mf] = __builtin_amdgcn_mfma_f32_16x16x32_bf16(af, bfr[mf], acc[mf], 0, 0, 0);
      }
    }
  const int co_r = co_base + wv * 16 + kg * 4;
  float b0 = bias[co_r], b1 = bias[co_r + 1], b2 = bias[co_r + 2], b3 = bias[co_r + 3];
#pragma unroll
  for (int mf = 0; mf < 4; ++mf) {
    int s = sp_base + mf * 16 + ln;
    int a = s >> 5, c = s & 31;
    size_t obase = (((size_t)(b << 12)) + (((a << 1) + ph) << 6) + (c << 1) + pw) << 8;
    ushort4 u = make_ushort4(f2bf(acc[mf][0] + b0), f2bf(acc[mf][1] + b1),
                             f2bf(acc[mf][2] + b2), f2bf(acc[mf][3] + b3));
    *(ushort4*)(out + obase + co_r) = u;
  }
}

// ---------------- BN stats over bf16 transposed (b, 4096, 256) ----------------
__global__ __launch_bounds__(256) void bnbt_stage1(const __hip_bfloat16* __restrict__ in, float* __restrict__ part) {
  int t = threadIdx.x, blk = blockIdx.x;  // 64 blocks
  float s[8] = {0,0,0,0,0,0,0,0}, s2[8] = {0,0,0,0,0,0,0,0};
  size_t base = ((size_t)blk * 256 + t) * 8;
  const size_t stride = 64 * 256 * 8;
  for (int it = 0; it < 256; ++it) {
    ushort4 u0 = *(const ushort4*)(in + base);
    ushort4 u1 = *(const ushort4*)(in + base + 4);
    float v[8] = {bf2f(u0.x), bf2f(u0.y), bf2f(u0.z), bf2f(u0.w),
                  bf2f(u1.x), bf2f(u1.y), bf2f(u1.z), bf2f(u1.w)};
#pragma unroll
    for (int q = 0; q < 8; ++q) { s[q] += v[q]; s2[q] += v[q] * v[q]; }
    base += stride;
  }
  __shared__ float ls[256][8], ls2[256][8];
#pragma unroll
  for (int q = 0; q < 8; ++q) { ls[t][q] = s[q]; ls2[t][q] = s2[q]; }
  __syncthreads();
  if (t < 32) {
#pragma unroll
    for (int q = 0; q < 8; ++q) {
      float a = 0.f, a2 = 0.f;
      for (int r = 0; r < 8; ++r) { a += ls[t + 32 * r][q]; a2 += ls2[t + 32 * r][q]; }
      part[blk * 256 + t * 8 + q] = a;
      part[16384 + blk * 256 + t * 8 + q] = a2;
    }
  }
}

__global__ __launch_bounds__(256) void bnbt_stage2(const float* __restrict__ part, float* __restrict__ stats) {
  int c = threadIdx.x;
  double s = 0.0, s2 = 0.0;
  for (int q = 0; q < 64; ++q) { s += part[q * 256 + c]; s2 += part[16384 + q * 256 + c]; }
  double m = s / 131072.0;
  double var = s2 / 131072.0 - m * m;
  stats[c] = (float)m;
  stats[256 + c] = (float)(1.0 / sqrt(var + 1e-5));
}

// BN+ReLU in-place on bf16 transposed
__global__ __launch_bounds__(256) void bn_apply_bt(__hip_bfloat16* __restrict__ io, const float* __restrict__ stats,
                                                   const float* __restrict__ g, const float* __restrict__ be) {
  int i = blockIdx.x * 256 + threadIdx.x;  // 4,194,304
  size_t off = (size_t)i * 8;
  int c0 = (i & 31) * 8;
  ushort4 u0 = *(const ushort4*)(io + off);
  ushort4 u1 = *(const ushort4*)(io + off + 4);
  float v[8] = {bf2f(u0.x), bf2f(u0.y), bf2f(u0.z), bf2f(u0.w),
                bf2f(u1.x), bf2f(u1.y), bf2f(u1.z), bf2f(u1.w)};
  unsigned short us[8];
#pragma unroll
  for (int q = 0; q < 8; ++q) {
    int c = c0 + q;
    float sc = stats[256 + c] * g[c];
    float sh = be[c] - stats[c] * sc;
    us[q] = f2bf(fmaxf(fmaf(v[q], sc, sh), 0.f));
  }
  *(ushort4*)(io + off) = make_ushort4(us[0], us[1], us[2], us[3]);
  *(ushort4*)(io + off + 4) = make_ushort4(us[4], us[5], us[6], us[7]);
}

// ---------------- encoder tiled conv (fp32, unchanged) ----------------
__device__ __forceinline__ void tile_fma(const float* Ws_, const float* Xs_, int co4, int sp4,
                                         float acc[4][4]) {
#pragma unroll
  for (int ci = 0; ci < 16; ++ci) {
    float4 wv = *(const float4*)(Ws_ + (ci << 6) + co4);
    float4 xv = *(const float4*)(Xs_ + (ci << 6) + sp4);
    acc[0][0] = fmaf(xv.x, wv.x, acc[0][0]);
    acc[0][1] = fmaf(xv.x, wv.y, acc[0][1]);
    acc[0][2] = fmaf(xv.x, wv.z, acc[0][2]);
    acc[0][3] = fmaf(xv.x, wv.w, acc[0][3]);
    acc[1][0] = fmaf(xv.y, wv.x, acc[1][0]);
    acc[1][1] = fmaf(xv.y, wv.y, acc[1][1]);
    acc[1][2] = fmaf(xv.y, wv.z, acc[1][2]);
    acc[1][3] = fmaf(xv.y, wv.w, acc[1][3]);
    acc[2][0] = fmaf(xv.z, wv.x, acc[2][0]);
    acc[2][1] = fmaf(xv.z, wv.y, acc[2][1]);
    acc[2][2] = fmaf(xv.z, wv.z, acc[2][2]);
    acc[2][3] = fmaf(xv.z, wv.w, acc[2][3]);
    acc[3][0] = fmaf(xv.w, wv.x, acc[3][0]);
    acc[3][1] = fmaf(xv.w, wv.y, acc[3][1]);
    acc[3][2] = fmaf(xv.w, wv.z, acc[3][2]);
    acc[3][3] = fmaf(xv.w, wv.w, acc[3][3]);
  }
}

__global__ __launch_bounds__(256) void conv_tiled(
    const float* __restrict__ in, const float* __restrict__ wt,
    const float* __restrict__ bias, float* __restrict__ out,
    int CI, int CO, int Hin, int Win, int Hout, int Wout,
    int KH, int KW, int stride, int pad) {
  __shared__ float Xs[16 * 64];
  __shared__ float Ws[16 * 64];
  const int tid = threadIdx.x;
  const int b = blockIdx.z;
  const int co_base = blockIdx.y << 6;
  const int sp_base = blockIdx.x << 6;
  const int lo = tid & 15, hi = tid >> 4;
  const int co4 = lo << 2, sp4 = hi << 2;
  const int HWin = Hin * Win, HWout = Hout * Wout;

  int oh0[4], ow0[4];
#pragma unroll
  for (int j = 0; j < 4; ++j) {
    int s = sp_base + (lo << 2) + j;
    oh0[j] = s / Wout; ow0[j] = s - oh0[j] * Wout;
  }
  float acc[4][4] = {{0.f,0.f,0.f,0.f},{0.f,0.f,0.f,0.f},{0.f,0.f,0.f,0.f},{0.f,0.f,0.f,0.f}};

  for (int kh = 0; kh < KH; ++kh)
    for (int kw = 0; kw < KW; ++kw) {
      const int t = kh * KW + kw;
      for (int ci0 = 0; ci0 < CI; ci0 += 16) {
        const float* ib = in + (size_t)(b * CI + ci0 + hi) * HWin;
        float v[4];
#pragma unroll
        for (int j = 0; j < 4; ++j) {
          int ih = oh0[j] * stride + kh - pad;
          int iw = ow0[j] * stride + kw - pad;
          v[j] = 0.f;
          if ((unsigned)ih < (unsigned)Hin && (unsigned)iw < (unsigned)Win)
            v[j] = ib[ih * Win + iw];
        }
        *(float4*)&Xs[(hi << 6) + (lo << 2)] = make_float4(v[0], v[1], v[2], v[3]);
        *(float4*)&Ws[(hi << 6) + (lo << 2)] =
            *(const float4*)&wt[((size_t)t * CI + ci0 + hi) * CO + co_base + (lo << 2)];
        __syncthreads();
        tile_fma(Ws, Xs, co4, sp4, acc);
        __syncthreads();
      }
    }
#pragma unroll
  for (int i = 0; i < 4; ++i) {
    int co = co_base + co4 + i;
    float bv = bias[co];
    float4 r = make_float4(acc[0][i] + bv, acc[1][i] + bv, acc[2][i] + bv, acc[3][i] + bv);
    *(float4*)&out[(size_t)(b * CO + co) * HWout + sp_base + sp4] = r;
  }
}

// ---------------- L10: deconv 256->3 + sigmoid (bf16 in) ----------------
__global__ __launch_bounds__(256) void deconv_final(const __hip_bfloat16* __restrict__ xt,
                                                    const float* __restrict__ wt,
                                                    const float* __restrict__ bias, float* __restrict__ out) {
  int phase = blockIdx.y, ph = phase >> 1, pw = phase & 1;
  int i = blockIdx.x * 256 + threadIdx.x;  // B*4096
  int b = i >> 12, p = i & 4095, a = p >> 6, c = p & 63;
  int khs[2], dhs[2], kws[2], dws[2];
  if (ph == 0) { khs[0]=1; dhs[0]=0; khs[1]=3; dhs[1]=-1; }
  else         { khs[0]=0; dhs[0]=1; khs[1]=2; dhs[1]=0; }
  if (pw == 0) { kws[0]=1; dws[0]=0; kws[1]=3; dws[1]=-1; }
  else         { kws[0]=0; dws[0]=1; kws[1]=2; dws[1]=0; }
  float a0 = bias[0], a1 = bias[1], a2 = bias[2];
  for (int ti = 0; ti < 2; ++ti)
    for (int tj = 0; tj < 2; ++tj) {
      int ih = a + dhs[ti], iw = c + dws[tj];
      if ((unsigned)ih >= 64u || (unsigned)iw >= 64u) continue;
      const __hip_bfloat16* xp = xt + ((((size_t)b << 12)) + (ih << 6) + iw) * 256;
      const float* wp = wt + (khs[ti] * 4 + kws[tj]) * 768;
      for (int ci = 0; ci < 256; ci += 4) {
        ushort4 u = *(const ushort4*)(xp + ci);
        float x0 = bf2f(u.x), x1 = bf2f(u.y), x2 = bf2f(u.z), x3 = bf2f(u.w);
        const float* w0 = wp + ci * 3;
        a0 = fmaf(x0, w0[0], a0); a1 = fmaf(x0, w0[1], a1); a2 = fmaf(x0, w0[2], a2);
        a0 = fmaf(x1, w0[3], a0); a1 = fmaf(x1, w0[4], a1); a2 = fmaf(x1, w0[5], a2);
        a0 = fmaf(x2, w0[6], a0); a1 = fmaf(x2, w0[7], a1); a2 = fmaf(x2, w0[8], a2);
        a0 = fmaf(x3, w0[9], a0); a1 = fmaf(x3, w0[10], a1); a2 = fmaf(x3, w0[11], a2);
      }
    }
  int oh = 2 * a + ph, ow = 2 * c + pw;
  size_t o = ((size_t)b * 3) * 16384 + (oh << 7) + ow;
  out[o] = 1.f / (1.f + __expf(-a0));
  out[o + 16384] = 1.f / (1.f + __expf(-a1));
  out[o + 32768] = 1.f / (1.f + __expf(-a2));
}

// ---------------- VQ ----------------
__global__ __launch_bounds__(256) void cb_norms(const float* __restrict__ emb, double* __restrict__ norms) {
  int k = blockIdx.x * 256 + threadIdx.x;
  if (k >= 512) return;
  double s = 0.0;
  for (int d = 0; d < 64; ++d) { double e = emb[(k << 6) + d]; s += e * e; }
  norms[k] = s;
}

__global__ __launch_bounds__(256) void vq_argmin(const float* __restrict__ enc, const float* __restrict__ emb,
                                                 const double* __restrict__ norms, int* __restrict__ cidx,
                                                 float* __restrict__ closest_out) {
  __shared__ float se[128 * 64];
  int tid = threadIdx.x;
  int r = blockIdx.x * 256 + tid;
  double ef[64];
  const float4* ep = (const float4*)(enc + ((size_t)r << 6));
#pragma unroll
  for (int q = 0; q < 16; ++q) {
    float4 v = ep[q];
    ef[4*q] = v.x; ef[4*q+1] = v.y; ef[4*q+2] = v.z; ef[4*q+3] = v.w;
  }
  double best = 1e300; int bi = 0;
  for (int q = 0; q < 4; ++q) {
    __syncthreads();
    for (int i = tid; i < 8192; i += 256) se[i] = emb[q * 8192 + i];
    __syncthreads();
    for (int k = 0; k < 128; ++k) {
      const float* cp = &se[k << 6];
      double dot = 0.0;
#pragma unroll
      for (int d = 0; d < 64; ++d) dot = fma(ef[d], (double)cp[d], dot);
      double d2 = norms[q * 128 + k] - 2.0 * dot;
      if (d2 < best) { best = d2; bi = q * 128 + k; }
    }
  }
  cidx[r] = bi;
  closest_out[r] = (float)bi;
}

__global__ __launch_bounds__(256) void vq_gather(const float* __restrict__ enc, const float* __restrict__ emb,
                                                 const int* __restrict__ cidx, __hip_bfloat16* __restrict__ qot,
                                                 float* __restrict__ part) {
  int tid = threadIdx.x;
  int i = blockIdx.x * 256 + tid;
  int r = i >> 6, d = i & 63;
  int k = cidx[r];
  float q = emb[(k << 6) + d];
  float e = enc[i];
  int b = r >> 10;
  int f = ((r & 1023) << 6) + d;
  int d_orig = f >> 10, p = f & 1023;
  qot[(((size_t)(b << 10)) + p) * 64 + d_orig] = __float2bfloat16(q);
  float df = q - e;
  __shared__ float red[256];
  red[tid] = df * df;
  __syncthreads();
  for (int st = 128; st > 0; st >>= 1) {
    if (tid < st) red[tid] += red[tid + st];
    __syncthreads();
  }
  if (tid == 0) part[blockIdx.x] = red[0];
}

__global__ __launch_bounds__(256) void qloss_final(const float* __restrict__ part, float* __restrict__ out) {
  int tid = threadIdx.x;
  double s = 0.0;
  for (int i = tid; i < 8192; i += 256) s += part[i];
  __shared__ double red[256];
  red[tid] = s;
  __syncthreads();
  for (int st = 128; st > 0; st >>= 1) {
    if (tid < st) red[tid] += red[tid + st];
    __syncthreads();
  }
  if (tid == 0) {
    double mean = red[0] / 2097152.0;
    out[0] = (float)(1.25 * mean);
  }
}

// ---------------- host ----------------
extern "C" void kernel_launch(void* const* d_in, const int* in_sizes, int n_in,
                              void* d_out, int out_size, void* d_ws, size_t ws_size,
                              hipStream_t stream) {
  const float* x     = (const float*)d_in[0];
  const float* emb   = (const float*)d_in[1];
  const float* e_w1  = (const float*)d_in[2];
  const float* e_b1  = (const float*)d_in[3];
  const float* e_g1  = (const float*)d_in[4];
  const float* e_be1 = (const float*)d_in[5];
  const float* e_w2  = (const float*)d_in[6];
  const float* e_b2  = (const float*)d_in[7];
  const float* e_g2  = (const float*)d_in[8];
  const float* e_be2 = (const float*)d_in[9];
  const float* e_rw1 = (const float*)d_in[10];
  const float* e_rb1 = (const float*)d_in[11];
  const float* e_rg1 = (const float*)d_in[12];
  const float* e_rbe1= (const float*)d_in[13];
  const float* e_rw2 = (const float*)d_in[14];
  const float* e_rb2 = (const float*)d_in[15];
  const float* e_rg2 = (const float*)d_in[16];
  const float* e_rbe2= (const float*)d_in[17];
  const float* e_pw  = (const float*)d_in[18];
  const float* e_pb  = (const float*)d_in[19];
  const float* d_pw  = (const float*)d_in[20];
  const float* d_pb  = (const float*)d_in[21];
  const float* d_rw1 = (const float*)d_in[22];
  const float* d_rb1 = (const float*)d_in[23];
  const float* d_rg1 = (const float*)d_in[24];
  const float* d_rbe1= (const float*)d_in[25];
  const float* d_rw2 = (const float*)d_in[26];
  const float* d_rb2 = (const float*)d_in[27];
  const float* d_rg2 = (const float*)d_in[28];
  const float* d_rbe2= (const float*)d_in[29];
  const float* d_tw1 = (const float*)d_in[30];
  const float* d_tb1 = (const float*)d_in[31];
  const float* d_tg1 = (const float*)d_in[32];
  const float* d_tbe1= (const float*)d_in[33];
  const float* d_tw2 = (const float*)d_in[34];
  const float* d_tb2 = (const float*)d_in[35];

  float* ws   = (float*)d_ws;
  float* BIG  = ws + OFF_BIG;
  float* BP   = ws + OFF_BP;
  float* ENC  = ws + OFF_ENC;
  float* S    = ws + OFF_S;
  float* W2T  = ws + OFF_W2T;
  float* RW1T = ws + OFF_RW1T;
  float* RW2T = ws + OFF_RW2T;
  float* PWT  = ws + OFF_PWT;
  float* TW2T = ws + OFF_TW2T;
  float* STATS= ws + OFF_STATS;
  double* NORM= (double*)(ws + OFF_NORM);
  int*   CIDX = (int*)(ws + OFF_CIDX);
  float* PART = ws + OFF_PART;
  float* STAT2= ws + OFF_STAT2;
  __hip_bfloat16* HT1  = (__hip_bfloat16*)(ws + OFF_HT1);
  __hip_bfloat16* HT2  = (__hip_bfloat16*)(ws + OFF_HT2);
  __hip_bfloat16* HT3  = (__hip_bfloat16*)(ws + OFF_HT3);
  __hip_bfloat16* QOT  = (__hip_bfloat16*)(ws + OFF_QOT);
  __hip_bfloat16* T9BT = (__hip_bfloat16*)(ws + OFF_BIG);
  __hip_bfloat16* DPWB = (__hip_bfloat16*)(ws + OFF_DPWB);
  __hip_bfloat16* DRW1B= (__hip_bfloat16*)(ws + OFF_DRW1B);
  __hip_bfloat16* DRW2B= (__hip_bfloat16*)(ws + OFF_DRW2B);
  __hip_bfloat16* TW1B = (__hip_bfloat16*)(ws + OFF_TW1B);
  float* outp = (float*)d_out;

  dim3 blk(256);

  // weight permutes + codebook norms
  wperm  <<<4096, blk, 0, stream>>>(e_w2,  W2T,  256, 256, 16, 1048576);
  wperm  <<<2304, blk, 0, stream>>>(e_rw1, RW1T, 256, 256, 9,  589824);
  wperm  <<<256,  blk, 0, stream>>>(e_rw2, RW2T, 256, 256, 1,  65536);
  wperm  <<<64,   blk, 0, stream>>>(e_pw,  PWT,  64,  256, 1,  16384);
  wpermT <<<48,   blk, 0, stream>>>(d_tw2, TW2T, 256, 3,   16, 12288);
  wpermb <<<64,   blk, 0, stream>>>(d_pw,  DPWB, 256, 64,  1,  16384);
  wpermb <<<2304, blk, 0, stream>>>(d_rw1, DRW1B,256, 256, 9,  589824);
  wpermb <<<2304, blk, 0, stream>>>(d_rw2, DRW2B,256, 256, 9,  589824);
  wpermbT<<<4096, blk, 0, stream>>>(d_tw1, TW1B, 256, 256, 16, 1048576);
  cb_norms<<<2, blk, 0, stream>>>(emb, NORM);

  // ---- encoder (fp32) ----
  conv1_k<<<dim3(16, 256, 32), blk, 0, stream>>>(x, e_w1, e_b1, BIG);
  bn_stats<<<256, blk, 0, stream>>>(BIG, STATS, 12, 32);
  bn_apply<<<32768, blk, 0, stream>>>((float4*)BIG, nullptr, (float4*)BIG, STATS, e_g1, e_be1, 12, 8388608);
  conv_tiled<<<dim3(16, 4, 32), blk, 0, stream>>>(BIG, W2T, e_b2, S, 256, 256, 64, 64, 32, 32, 4, 4, 2, 1);
  bn_stats<<<256, blk, 0, stream>>>(S, STATS, 10, 32);
  bn_apply<<<8192, blk, 0, stream>>>((float4*)S, nullptr, (float4*)S, STATS, e_g2, e_be2, 10, 2097152);
  conv_tiled<<<dim3(16, 4, 32), blk, 0, stream>>>(S, RW1T, e_rb1, BP, 256, 256, 32, 32, 32, 32, 3, 3, 1, 1);
  bn_stats<<<256, blk, 0, stream>>>(BP, STATS, 10, 32);
  bn_apply<<<8192, blk, 0, stream>>>((float4*)BP, (float4*)S, (float4*)BP, STATS, e_rg1, e_rbe1, 10, 2097152);
  conv_tiled<<<dim3(16, 4, 32), blk, 0, stream>>>(BP, RW2T, e_rb2, S, 256, 256, 32, 32, 32, 32, 1, 1, 1, 0);
  bn_stats<<<256, blk, 0, stream>>>(S, STATS, 10, 32);
  bn_apply<<<8192, blk, 0, stream>>>((float4*)S, (float4*)BP, (float4*)S, STATS, e_rg2, e_rbe2, 10, 2097152);
  conv_tiled<<<dim3(16, 1, 32), blk, 0, stream>>>(S, PWT, e_pb, ENC, 256, 64, 32, 32, 32, 32, 1, 1, 1, 0);

  // ---- VQ ----
  vq_argmin<<<128, blk, 0, stream>>>(ENC, emb, NORM, CIDX, outp + OUT_CLOSEST);
  vq_gather<<<8192, blk, 0, stream>>>(ENC, emb, CIDX, QOT, PART);
  qloss_final<<<1, blk, 0, stream>>>(PART, outp + OUT_QLOSS);

  // ---- decoder (bf16 MFMA) ----
  // L6: 1x1 64->256
  mconv<64, 1, 1, 0><<<dim3(16, 4, 32), blk, 0, stream>>>(QOT, DPWB, d_pb, S, 256);
  fp32_to_bt<<<4096, blk, 0, stream>>>(S, HT1);
  // L7: res 3x3
  mconv<256, 3, 3, 1><<<dim3(16, 4, 32), blk, 0, stream>>>(HT1, DRW1B, d_rb1, BP, 256);
  bn_stats<<<256, blk, 0, stream>>>(BP, STATS, 10, 32);
  bn_apply_td<<<4096, blk, 0, stream>>>(BP, S, S, HT2, STATS, d_rg1, d_rbe1);
  // L8: res 3x3
  mconv<256, 3, 3, 1><<<dim3(16, 4, 32), blk, 0, stream>>>(HT2, DRW2B, d_rb2, BP, 256);
  bn_stats<<<256, blk, 0, stream>>>(BP, STATS, 10, 32);
  bn_apply_td<<<4096, blk, 0, stream>>>(BP, S, nullptr, HT3, STATS, d_rg2, d_rbe2);
  // L9: deconv 256->256 (writes bf16 transposed t9)
  mdeconv<<<dim3(16, 4, 128), blk, 0, stream>>>(HT3, TW1B, d_tb1, T9BT);
  bnbt_stage1<<<64, blk, 0, stream>>>(T9BT, STAT2);
  bnbt_stage2<<<1, blk, 0, stream>>>(STAT2, STATS);
  bn_apply_bt<<<16384, blk, 0, stream>>>(T9BT, STATS, d_tg1, d_tbe1);
  // L10: deconv 256->3 + sigmoid
  deconv_final<<<dim3(512, 4), blk, 0, stream>>>(T9BT, TW2T, d_tb2, outp);
}